// Round 1
// baseline (774.387 us; speedup 1.0000x reference)
//
#include <hip/hip_runtime.h>

typedef __attribute__((ext_vector_type(4))) float f32x4;
typedef __attribute__((ext_vector_type(8))) short bf16x8;
typedef __attribute__((ext_vector_type(2))) unsigned int u32x2;
typedef __attribute__((ext_vector_type(4))) unsigned int u32x4;

static __device__ __forceinline__ unsigned short f2bf(float f) {
    unsigned u = __builtin_bit_cast(unsigned, f);
    u += 0x7fffu + ((u >> 16) & 1u);   // RNE
    return (unsigned short)(u >> 16);
}
static __device__ __forceinline__ unsigned pack2(float a, float b) {
    return (unsigned)f2bf(a) | ((unsigned)f2bf(b) << 16);
}

// ---------------------------------------------------------------------------
// C[128 x N] = A[128 x K(fp32)] * B[K x N(fp32)], bf16 MFMA, fp32 accum.
// grid.x = N/64, grid.y = ksplit. colmap=1 applies DeepSeek q-nope col map.
// atomic_out=1 -> atomicAdd partials (caller must zero C).
// ---------------------------------------------------------------------------
__global__ __launch_bounds__(256)
void gemm128(const float* __restrict__ A, int lda,
             const float* __restrict__ Bm, int ldb,
             float* __restrict__ C, int ldc,
             int kchunk, int colmap, int atomic_out)
{
    __shared__ __align__(16) unsigned short As[128 * 72];
    __shared__ __align__(16) unsigned short Bs[64 * 72];

    const int tid = threadIdx.x;
    const int w = tid >> 6, l = tid & 63, lg = l >> 4, l15 = l & 15;
    const int n0 = blockIdx.x * 64;
    const int pcol = colmap ? ((n0 >> 7) * 192 + (n0 & 127)) : n0;
    const size_t k0base = (size_t)blockIdx.y * (size_t)kchunk;

    f32x4 acc[2][4];
    const f32x4 fzero = {0.f, 0.f, 0.f, 0.f};
#pragma unroll
    for (int a = 0; a < 2; a++)
#pragma unroll
        for (int b2 = 0; b2 < 4; b2++) acc[a][b2] = fzero;

    for (int kt = 0; kt < kchunk; kt += 64) {
        const size_t k0 = k0base + (size_t)kt;
        // ---- stage A tile (128x64), cvt to bf16
        {
            const int c4 = (tid & 15) * 4;
#pragma unroll
            for (int j = 0; j < 8; j++) {
                const int r = (tid >> 4) + 16 * j;
                f32x4 v = *(const f32x4*)(A + (size_t)r * lda + k0 + c4);
                u32x2 wv = { pack2(v[0], v[1]), pack2(v[2], v[3]) };
                *(u32x2*)&As[r * 72 + c4] = wv;
            }
        }
        // ---- stage B tile (64x64) transposed -> Bs[n][k], 2 k's per dword
        {
            const int nb = (tid & 15) * 4;
            unsigned* bd = (unsigned*)Bs;
#pragma unroll
            for (int i = 0; i < 2; i++) {
                const int kk = (tid >> 4) + 16 * i;      // k-pair index 0..31
                const float* bp = Bm + (k0 + (size_t)(2 * kk)) * (size_t)ldb + pcol + nb;
                f32x4 r0 = *(const f32x4*)bp;
                f32x4 r1 = *(const f32x4*)(bp + ldb);
#pragma unroll
                for (int j = 0; j < 4; j++)
                    bd[(nb + j) * 36 + kk] = pack2(r0[j], r1[j]);
            }
        }
        __syncthreads();
#pragma unroll
        for (int ks = 0; ks < 2; ks++) {
            bf16x8 bfr[4];
#pragma unroll
            for (int nf = 0; nf < 4; nf++)
                bfr[nf] = *(const bf16x8*)&Bs[(16 * nf + l15) * 72 + 32 * ks + 8 * lg];
#pragma unroll
            for (int mf = 0; mf < 2; mf++) {
                bf16x8 af = *(const bf16x8*)&As[(32 * w + 16 * mf + l15) * 72 + 32 * ks + 8 * lg];
#pragma unroll
                for (int nf = 0; nf < 4; nf++)
                    acc[mf][nf] = __builtin_amdgcn_mfma_f32_16x16x32_bf16(af, bfr[nf], acc[mf][nf], 0, 0, 0);
            }
        }
        __syncthreads();
    }
    // ---- epilogue
#pragma unroll
    for (int mf = 0; mf < 2; mf++) {
#pragma unroll
        for (int nf = 0; nf < 4; nf++) {
            const int m0 = 32 * w + 16 * mf + 4 * lg;
            const int cn = n0 + 16 * nf + l15;
            if (atomic_out) {
#pragma unroll
                for (int r = 0; r < 4; r++)
                    atomicAdd(&C[(size_t)(m0 + r) * ldc + cn], acc[mf][nf][r]);
            } else {
#pragma unroll
                for (int r = 0; r < 4; r++)
                    C[(size_t)(m0 + r) * ldc + cn] = acc[mf][nf][r];
            }
        }
    }
}

// ---------------------------------------------------------------------------
// Flash-decode attention. grid = (B, NSPLIT=2), block = 512 (8 waves).
// Wave w owns heads 16w..16w+15. Swapped QK^T: mfma(K, Q) -> scores^T so the
// softmax axis is in-lane + lanes {l, l^16, l^32, l^48}.
// Outputs UNNORMALIZED partial O plus (m, l) for the combine pass.
// ---------------------------------------------------------------------------
__global__ __launch_bounds__(512)
void attn_fwd(const float* __restrict__ kc, const float* __restrict__ vc,
              const float* __restrict__ qws, const float* __restrict__ kvws,
              const int* __restrict__ seq_lens, const int* __restrict__ slot_map,
              float* __restrict__ Opart, float* __restrict__ m_ws, float* __restrict__ l_ws)
{
    __shared__ __align__(16) unsigned short Ks [128 * 136];
    __shared__ __align__(16) unsigned short Vts[128 * 136];
    __shared__ __align__(16) unsigned short Ps [128 * 136];

    const int b = blockIdx.x, split = blockIdx.y;
    const int seq = seq_lens[b], slot = slot_map[b];
    const int nt = (seq + 127) >> 7;
    const int half = (nt + 1) >> 1;
    const int t0 = split ? half : 0;
    const int t1 = split ? nt : half;

    const int tid = threadIdx.x, w = tid >> 6, l = tid & 63, lg = l >> 4, l15 = l & 15;
    const int h = 16 * w + l15;
    const float scale = 0.088388347648318447f;   // 1/sqrt(128)

    // Q fragments (this lane's head, d = 32*ks + 8*lg + j)
    bf16x8 qf[4];
    {
        const float* qrow = qws + (size_t)b * 16384 + (size_t)h * 128;
#pragma unroll
        for (int ks = 0; ks < 4; ks++) {
            const float* p = qrow + 32 * ks + 8 * lg;
            f32x4 a = *(const f32x4*)p;
            f32x4 c = *(const f32x4*)(p + 4);
            u32x4 t = { pack2(a[0] * scale, a[1] * scale), pack2(a[2] * scale, a[3] * scale),
                        pack2(c[0] * scale, c[1] * scale), pack2(c[2] * scale, c[3] * scale) };
            qf[ks] = __builtin_bit_cast(bf16x8, t);
        }
    }

    f32x4 accO[8];
    const f32x4 fzero = {0.f, 0.f, 0.f, 0.f};
#pragma unroll
    for (int i = 0; i < 8; i++) accO[i] = fzero;
    float m_run = -__builtin_inff(), l_run = 0.0f;

    const float* knew = kvws + b * 256;
    const float* vnew = knew + 128;

    for (int t = t0; t < t1; ++t) {
        const int s0 = t << 7;
        // ---- stage K tile [128 s][128 d] -> bf16
        {
            const int r = tid >> 3;
            const int cb = (tid & 7) * 16;
#pragma unroll
            for (int pass = 0; pass < 2; ++pass) {
                const int rr = r + 64 * pass;
                const int s = s0 + rr;
                const float* src = (s == slot) ? knew : (kc + ((size_t)b * 4096 + s) * 128);
                f32x4 v0 = *(const f32x4*)(src + cb);
                f32x4 v1 = *(const f32x4*)(src + cb + 4);
                f32x4 v2 = *(const f32x4*)(src + cb + 8);
                f32x4 v3 = *(const f32x4*)(src + cb + 12);
                u32x4 w0 = { pack2(v0[0], v0[1]), pack2(v0[2], v0[3]),
                             pack2(v1[0], v1[1]), pack2(v1[2], v1[3]) };
                u32x4 w1 = { pack2(v2[0], v2[1]), pack2(v2[2], v2[3]),
                             pack2(v3[0], v3[1]), pack2(v3[2], v3[3]) };
                *(u32x4*)&Ks[rr * 136 + cb] = w0;
                *(u32x4*)&Ks[rr * 136 + cb + 8] = w1;
            }
        }
        // ---- stage V^T tile: Vts[d][s], 2 s per dword
        {
            const int d4 = (tid & 31) * 4;
            const int spb = tid >> 5;
            unsigned* vt = (unsigned*)Vts;
#pragma unroll
            for (int i = 0; i < 4; i++) {
                const int sp = spb + 16 * i;           // s-pair 0..63
                const int s1 = s0 + 2 * sp, s2 = s1 + 1;
                const float* r1 = (s1 == slot) ? vnew : (vc + ((size_t)b * 4096 + s1) * 128);
                const float* r2 = (s2 == slot) ? vnew : (vc + ((size_t)b * 4096 + s2) * 128);
                f32x4 a = *(const f32x4*)(r1 + d4);
                f32x4 c = *(const f32x4*)(r2 + d4);
#pragma unroll
                for (int j = 0; j < 4; j++)
                    vt[(d4 + j) * 68 + sp] = pack2(a[j], c[j]);
            }
        }
        __syncthreads();

        // ---- scores^T = K * Q^T  (M=s, N=h, K=d)
        f32x4 accS[8];
#pragma unroll
        for (int sf = 0; sf < 8; sf++) accS[sf] = fzero;
#pragma unroll
        for (int ks = 0; ks < 4; ks++) {
#pragma unroll
            for (int sf = 0; sf < 8; sf++) {
                bf16x8 kf = *(const bf16x8*)&Ks[(16 * sf + l15) * 136 + 32 * ks + 8 * lg];
                accS[sf] = __builtin_amdgcn_mfma_f32_16x16x32_bf16(kf, qf[ks], accS[sf], 0, 0, 0);
            }
        }
        // ---- mask + online softmax (lane's s = s0 + 16*sf + 4*lg + r)
        float tmax = -__builtin_inff();
#pragma unroll
        for (int sf = 0; sf < 8; sf++) {
#pragma unroll
            for (int r = 0; r < 4; r++) {
                const int s = s0 + 16 * sf + 4 * lg + r;
                float sc = (s < seq) ? accS[sf][r] : -__builtin_inff();
                accS[sf][r] = sc;
                tmax = fmaxf(tmax, sc);
            }
        }
        tmax = fmaxf(tmax, __shfl_xor(tmax, 16));
        tmax = fmaxf(tmax, __shfl_xor(tmax, 32));
        const float mnew = fmaxf(m_run, tmax);
        const float so = __expf(m_run - mnew);
        float lsum = 0.f;
        float pv[8][4];
#pragma unroll
        for (int sf = 0; sf < 8; sf++) {
#pragma unroll
            for (int r = 0; r < 4; r++) {
                const float p = __expf(accS[sf][r] - mnew);  // exp(-inf)=0 masks
                pv[sf][r] = p;
                lsum += p;
            }
        }
        lsum += __shfl_xor(lsum, 16);
        lsum += __shfl_xor(lsum, 32);
        l_run = l_run * so + lsum;
        m_run = mnew;
#pragma unroll
        for (int i = 0; i < 8; i++) accO[i] *= so;

        // ---- P -> LDS (wave-private rows, no barrier needed)
        {
            unsigned* pd = (unsigned*)Ps;
#pragma unroll
            for (int sf = 0; sf < 8; sf++) {
                pd[h * 68 + 8 * sf + 2 * lg + 0] = pack2(pv[sf][0], pv[sf][1]);
                pd[h * 68 + 8 * sf + 2 * lg + 1] = pack2(pv[sf][2], pv[sf][3]);
            }
        }
        // ---- O^T += V^T * P^T  (M=d, N=h, K=s)
        bf16x8 pf[4];
#pragma unroll
        for (int ks = 0; ks < 4; ks++)
            pf[ks] = *(const bf16x8*)&Ps[h * 136 + 32 * ks + 8 * lg];
#pragma unroll
        for (int df = 0; df < 8; df++) {
#pragma unroll
            for (int ks = 0; ks < 4; ks++) {
                bf16x8 vf = *(const bf16x8*)&Vts[(16 * df + l15) * 136 + 32 * ks + 8 * lg];
                accO[df] = __builtin_amdgcn_mfma_f32_16x16x32_bf16(vf, pf[ks], accO[df], 0, 0, 0);
            }
        }
        __syncthreads();
    }
    // ---- epilogue: unnormalized partial O, plus (m, l)
    const size_t base = ((size_t)(b * 2 + split)) * 16384 + (size_t)h * 128;
#pragma unroll
    for (int df = 0; df < 8; df++)
        *(f32x4*)&Opart[base + 16 * df + 4 * lg] = accO[df];
    if (lg == 0) {
        m_ws[(b * 2 + split) * 128 + h] = m_run;
        l_ws[(b * 2 + split) * 128 + h] = l_run;
    }
}

// ---------------------------------------------------------------------------
// Combine the 2 S-splits: O = (a1*O1 + a2*O2) / (a1*l1 + a2*l2)
// ---------------------------------------------------------------------------
__global__ __launch_bounds__(256)
void combine2(const float* __restrict__ Opart, const float* __restrict__ m_ws,
              const float* __restrict__ l_ws, float* __restrict__ attn)
{
    const int idx = blockIdx.x * 256 + threadIdx.x;  // 0..524287
    const int d4 = (idx & 31) * 4;
    const int hh = (idx >> 5) & 127;
    const int b = idx >> 12;
    const float m1 = m_ws[(b * 2) * 128 + hh], m2 = m_ws[(b * 2 + 1) * 128 + hh];
    const float l1 = l_ws[(b * 2) * 128 + hh], l2 = l_ws[(b * 2 + 1) * 128 + hh];
    const float m = fmaxf(m1, m2);
    const float a1 = (l1 > 0.f) ? __expf(m1 - m) : 0.f;
    const float a2 = (l2 > 0.f) ? __expf(m2 - m) : 0.f;
    const float inv = 1.0f / (a1 * l1 + a2 * l2);
    f32x4 o1 = *(const f32x4*)&Opart[((size_t)(b * 2)) * 16384 + (size_t)hh * 128 + d4];
    f32x4 o2 = *(const f32x4*)&Opart[((size_t)(b * 2 + 1)) * 16384 + (size_t)hh * 128 + d4];
    f32x4 r = (o1 * a1 + o2 * a2) * inv;
    *(f32x4*)&attn[(size_t)b * 16384 + (size_t)hh * 128 + d4] = r;
}

// ---------------------------------------------------------------------------
extern "C" void kernel_launch(void* const* d_in, const int* in_sizes, int n_in,
                              void* d_out, int out_size, void* d_ws, size_t ws_size,
                              hipStream_t stream)
{
    const float* hidden  = (const float*)d_in[0];
    const float* k_cache = (const float*)d_in[1];
    const float* v_cache = (const float*)d_in[2];
    const float* Wq      = (const float*)d_in[3];
    const float* Wkv     = (const float*)d_in[4];
    const float* Wo      = (const float*)d_in[5];
    // d_in[6] positions: unused by the reference
    const int* slot_map  = (const int*)d_in[7];
    const int* seq_lens  = (const int*)d_in[8];
    float* out = (float*)d_out;

    float* ws      = (float*)d_ws;
    float* q_ws    = ws;                 // 128*16384            = 2,097,152 f
    float* attn_ws = ws + 2097152;       // 128*16384            = 2,097,152 f
    float* kv_ws   = ws + 4194304;       // 128*256              =    32,768 f
    float* Opart   = ws + 4227072;       // 128*2*16384          = 4,194,304 f
    float* m_ws    = ws + 8421376;       // 128*2*128            =    32,768 f
    float* l_ws    = ws + 8454144;       //                      =    32,768 f

    hipMemsetAsync(kv_ws, 0, 32768 * sizeof(float), stream);
    hipMemsetAsync(d_out, 0, (size_t)out_size * sizeof(float), stream);

    // kv = hidden @ Wkv[:, :256]   (K-split 16, atomic)
    gemm128<<<dim3(4, 16), 256, 0, stream>>>(hidden, 5120, Wkv, 576, kv_ws, 256, 320, 0, 1);
    // q_nope = hidden @ Wq (nope columns only; head-mapped cols)
    gemm128<<<dim3(256, 1), 256, 0, stream>>>(hidden, 5120, Wq, 24576, q_ws, 16384, 5120, 1, 0);
    // attention (2 S-splits per batch)
    attn_fwd<<<dim3(128, 2), 512, 0, stream>>>(k_cache, v_cache, q_ws, kv_ws,
                                               seq_lens, slot_map, Opart, m_ws, l_ws);
    combine2<<<dim3(2048), 256, 0, stream>>>(Opart, m_ws, l_ws, attn_ws);
    // out = attn @ Wo   (K-split 4, atomic into zeroed d_out)
    gemm128<<<dim3(80, 4), 256, 0, stream>>>(attn_ws, 16384, Wo, 5120, out, 5120, 4096, 0, 1);
}

// Round 2
// 441.570 us; speedup vs baseline: 1.7537x; 1.7537x over previous
//
#include <hip/hip_runtime.h>

typedef __attribute__((ext_vector_type(4))) float f32x4;
typedef __attribute__((ext_vector_type(8))) short bf16x8;
typedef __attribute__((ext_vector_type(2))) unsigned int u32x2;
typedef __attribute__((ext_vector_type(4))) unsigned int u32x4;

static __device__ __forceinline__ unsigned short f2bf(float f) {
    unsigned u = __builtin_bit_cast(unsigned, f);
    u += 0x7fffu + ((u >> 16) & 1u);   // RNE
    return (unsigned short)(u >> 16);
}
static __device__ __forceinline__ unsigned pack2(float a, float b) {
    return (unsigned)f2bf(a) | ((unsigned)f2bf(b) << 16);
}

// ---------------------------------------------------------------------------
// C[128 x N] = A[128 x K(fp32)] * B[K x N(fp32)], bf16 MFMA, fp32 accum.
// 1D grid = ntiles * nsplit; bx = blockIdx.x / nsplit (N-tile),
// by = blockIdx.x % nsplit (K-split) -> K-split round-robins XCDs so each
// XCD L2 keeps one A-slice hot. Register-prefetch double buffering.
// ---------------------------------------------------------------------------
__global__ __launch_bounds__(256, 4)
void gemm128(const float* __restrict__ A, int lda,
             const float* __restrict__ Bm, int ldb,
             float* __restrict__ C, int ldc,
             int kchunk, int nsplit, int colmap, int atomic_out)
{
    __shared__ __align__(16) unsigned short As[128 * 72];
    __shared__ __align__(16) unsigned short Bs[64 * 66];   // stride 33 dwords

    const int tid = threadIdx.x;
    const int w = tid >> 6, l = tid & 63, lg = l >> 4, l15 = l & 15;
    const int bx = blockIdx.x / nsplit;
    const int by = blockIdx.x % nsplit;
    const int n0 = bx * 64;
    const int pcol = colmap ? ((n0 >> 7) * 192 + (n0 & 127)) : n0;
    const size_t k0base = (size_t)by * (size_t)kchunk;

    const int ac4 = (tid & 15) * 4;   // A col within tile
    const int ar  = tid >> 4;         // A row base
    const int bnb = (tid & 15) * 4;   // B col within tile
    const int bkk = tid >> 4;         // B k-pair base

    f32x4 aReg[8];
    f32x4 bReg[2][2];

    auto loadTiles = [&](size_t k0) {
#pragma unroll
        for (int j = 0; j < 8; j++)
            aReg[j] = *(const f32x4*)(A + (size_t)(ar + 16 * j) * lda + k0 + ac4);
#pragma unroll
        for (int i = 0; i < 2; i++) {
            const float* bp = Bm + (k0 + (size_t)(2 * (bkk + 16 * i))) * (size_t)ldb + pcol + bnb;
            bReg[i][0] = *(const f32x4*)bp;
            bReg[i][1] = *(const f32x4*)(bp + ldb);
        }
    };
    auto storeTiles = [&]() {
#pragma unroll
        for (int j = 0; j < 8; j++) {
            u32x2 wv = { pack2(aReg[j][0], aReg[j][1]), pack2(aReg[j][2], aReg[j][3]) };
            *(u32x2*)&As[(ar + 16 * j) * 72 + ac4] = wv;
        }
        unsigned* bd = (unsigned*)Bs;
#pragma unroll
        for (int i = 0; i < 2; i++)
#pragma unroll
            for (int j = 0; j < 4; j++)
                bd[(bnb + j) * 33 + bkk + 16 * i] = pack2(bReg[i][0][j], bReg[i][1][j]);
    };

    f32x4 acc[2][4];
    const f32x4 fzero = {0.f, 0.f, 0.f, 0.f};
#pragma unroll
    for (int a = 0; a < 2; a++)
#pragma unroll
        for (int b2 = 0; b2 < 4; b2++) acc[a][b2] = fzero;

    loadTiles(k0base);
    for (int kt = 0; kt < kchunk; kt += 64) {
        storeTiles();
        __syncthreads();
        if (kt + 64 < kchunk) loadTiles(k0base + (size_t)kt + 64);
#pragma unroll
        for (int ks = 0; ks < 2; ks++) {
            bf16x8 bfr[4];
#pragma unroll
            for (int nf = 0; nf < 4; nf++)
                bfr[nf] = *(const bf16x8*)&Bs[(16 * nf + l15) * 66 + 32 * ks + 8 * lg];
#pragma unroll
            for (int mf = 0; mf < 2; mf++) {
                bf16x8 af = *(const bf16x8*)&As[(32 * w + 16 * mf + l15) * 72 + 32 * ks + 8 * lg];
#pragma unroll
                for (int nf = 0; nf < 4; nf++)
                    acc[mf][nf] = __builtin_amdgcn_mfma_f32_16x16x32_bf16(af, bfr[nf], acc[mf][nf], 0, 0, 0);
            }
        }
        __syncthreads();
    }
#pragma unroll
    for (int mf = 0; mf < 2; mf++) {
#pragma unroll
        for (int nf = 0; nf < 4; nf++) {
            const int m0 = 32 * w + 16 * mf + 4 * lg;
            const int cn = n0 + 16 * nf + l15;
            if (atomic_out) {
#pragma unroll
                for (int r = 0; r < 4; r++)
                    atomicAdd(&C[(size_t)(m0 + r) * ldc + cn], acc[mf][nf][r]);
            } else {
#pragma unroll
                for (int r = 0; r < 4; r++)
                    C[(size_t)(m0 + r) * ldc + cn] = acc[mf][nf][r];
            }
        }
    }
}

// ---------------------------------------------------------------------------
// Flash-decode attention, register-prefetch double-buffered K/V staging.
// grid = (B, NSPLIT=2), block = 512 (8 waves). Swapped QK^T (mfma(K,Q)).
// ---------------------------------------------------------------------------
__global__ __launch_bounds__(512)
void attn_fwd(const float* __restrict__ kc, const float* __restrict__ vc,
              const float* __restrict__ qws, const float* __restrict__ kvws,
              const int* __restrict__ seq_lens, const int* __restrict__ slot_map,
              float* __restrict__ Opart, float* __restrict__ m_ws, float* __restrict__ l_ws)
{
    __shared__ __align__(16) unsigned short Ks [128 * 136];
    __shared__ __align__(16) unsigned short Vts[128 * 136];
    __shared__ __align__(16) unsigned short Ps [128 * 136];

    const int b = blockIdx.x, split = blockIdx.y;
    const int seq = seq_lens[b], slot = slot_map[b];
    const int nt = (seq + 127) >> 7;
    const int half = (nt + 1) >> 1;
    const int t0 = split ? half : 0;
    const int t1 = split ? nt : half;

    const int tid = threadIdx.x, w = tid >> 6, l = tid & 63, lg = l >> 4, l15 = l & 15;
    const int h = 16 * w + l15;
    const float scale = 0.088388347648318447f;   // 1/sqrt(128)

    const float* knew = kvws + b * 256;
    const float* vnew = knew + 128;

    // Q fragments
    bf16x8 qf[4];
    {
        const float* qrow = qws + (size_t)b * 16384 + (size_t)h * 128;
#pragma unroll
        for (int ks = 0; ks < 4; ks++) {
            const float* p = qrow + 32 * ks + 8 * lg;
            f32x4 a = *(const f32x4*)p;
            f32x4 c = *(const f32x4*)(p + 4);
            u32x4 t = { pack2(a[0] * scale, a[1] * scale), pack2(a[2] * scale, a[3] * scale),
                        pack2(c[0] * scale, c[1] * scale), pack2(c[2] * scale, c[3] * scale) };
            qf[ks] = __builtin_bit_cast(bf16x8, t);
        }
    }

    // staging register slots
    f32x4 kReg[2][4];
    f32x4 vReg[4][2];
    const int kr  = tid >> 3;
    const int kcb = (tid & 7) * 16;
    const int vd4 = (tid & 31) * 4;
    const int vsp = tid >> 5;

    auto loadKV = [&](int t) {
        const int s0 = t << 7;
#pragma unroll
        for (int pass = 0; pass < 2; ++pass) {
            const int s = s0 + kr + 64 * pass;
            const float* src = (s == slot) ? knew : (kc + ((size_t)b * 4096 + s) * 128);
            kReg[pass][0] = *(const f32x4*)(src + kcb);
            kReg[pass][1] = *(const f32x4*)(src + kcb + 4);
            kReg[pass][2] = *(const f32x4*)(src + kcb + 8);
            kReg[pass][3] = *(const f32x4*)(src + kcb + 12);
        }
#pragma unroll
        for (int i = 0; i < 4; i++) {
            const int sp = vsp + 16 * i;
            const int s1 = s0 + 2 * sp, s2 = s1 + 1;
            const float* r1 = (s1 == slot) ? vnew : (vc + ((size_t)b * 4096 + s1) * 128);
            const float* r2 = (s2 == slot) ? vnew : (vc + ((size_t)b * 4096 + s2) * 128);
            vReg[i][0] = *(const f32x4*)(r1 + vd4);
            vReg[i][1] = *(const f32x4*)(r2 + vd4);
        }
    };
    auto storeKV = [&]() {
#pragma unroll
        for (int pass = 0; pass < 2; ++pass) {
            const int rr = kr + 64 * pass;
            u32x4 w0 = { pack2(kReg[pass][0][0], kReg[pass][0][1]), pack2(kReg[pass][0][2], kReg[pass][0][3]),
                         pack2(kReg[pass][1][0], kReg[pass][1][1]), pack2(kReg[pass][1][2], kReg[pass][1][3]) };
            u32x4 w1 = { pack2(kReg[pass][2][0], kReg[pass][2][1]), pack2(kReg[pass][2][2], kReg[pass][2][3]),
                         pack2(kReg[pass][3][0], kReg[pass][3][1]), pack2(kReg[pass][3][2], kReg[pass][3][3]) };
            *(u32x4*)&Ks[rr * 136 + kcb] = w0;
            *(u32x4*)&Ks[rr * 136 + kcb + 8] = w1;
        }
        unsigned* vt = (unsigned*)Vts;
#pragma unroll
        for (int i = 0; i < 4; i++) {
            const int sp = vsp + 16 * i;
#pragma unroll
            for (int j = 0; j < 4; j++)
                vt[(vd4 + j) * 68 + sp] = pack2(vReg[i][0][j], vReg[i][1][j]);
        }
    };

    f32x4 accO[8];
    const f32x4 fzero = {0.f, 0.f, 0.f, 0.f};
#pragma unroll
    for (int i = 0; i < 8; i++) accO[i] = fzero;
    float m_run = -__builtin_inff(), l_run = 0.0f;

    if (t0 < t1) loadKV(t0);

    for (int t = t0; t < t1; ++t) {
        const int s0 = t << 7;
        storeKV();
        __syncthreads();
        if (t + 1 < t1) loadKV(t + 1);

        // ---- scores^T = K * Q^T
        f32x4 accS[8];
#pragma unroll
        for (int sf = 0; sf < 8; sf++) accS[sf] = fzero;
#pragma unroll
        for (int ks = 0; ks < 4; ks++) {
#pragma unroll
            for (int sf = 0; sf < 8; sf++) {
                bf16x8 kf = *(const bf16x8*)&Ks[(16 * sf + l15) * 136 + 32 * ks + 8 * lg];
                accS[sf] = __builtin_amdgcn_mfma_f32_16x16x32_bf16(kf, qf[ks], accS[sf], 0, 0, 0);
            }
        }
        // ---- mask + online softmax (lane's s = s0 + 16*sf + 4*lg + r)
        float tmax = -__builtin_inff();
#pragma unroll
        for (int sf = 0; sf < 8; sf++) {
#pragma unroll
            for (int r = 0; r < 4; r++) {
                const int s = s0 + 16 * sf + 4 * lg + r;
                float sc = (s < seq) ? accS[sf][r] : -__builtin_inff();
                accS[sf][r] = sc;
                tmax = fmaxf(tmax, sc);
            }
        }
        tmax = fmaxf(tmax, __shfl_xor(tmax, 16));
        tmax = fmaxf(tmax, __shfl_xor(tmax, 32));
        const float mnew = fmaxf(m_run, tmax);
        const float so = __expf(m_run - mnew);
        float lsum = 0.f;
#pragma unroll
        for (int sf = 0; sf < 8; sf++) {
#pragma unroll
            for (int r = 0; r < 4; r++) {
                const float p = __expf(accS[sf][r] - mnew);  // exp(-inf)=0 masks
                accS[sf][r] = p;
                lsum += p;
            }
        }
        lsum += __shfl_xor(lsum, 16);
        lsum += __shfl_xor(lsum, 32);
        l_run = l_run * so + lsum;
        m_run = mnew;
#pragma unroll
        for (int i = 0; i < 8; i++) accO[i] *= so;

        // ---- P -> LDS (wave-private rows)
        {
            unsigned* pd = (unsigned*)Ps;
#pragma unroll
            for (int sf = 0; sf < 8; sf++) {
                pd[h * 68 + 8 * sf + 2 * lg + 0] = pack2(accS[sf][0], accS[sf][1]);
                pd[h * 68 + 8 * sf + 2 * lg + 1] = pack2(accS[sf][2], accS[sf][3]);
            }
        }
        // ---- O^T += V^T * P^T
        bf16x8 pf[4];
#pragma unroll
        for (int ks = 0; ks < 4; ks++)
            pf[ks] = *(const bf16x8*)&Ps[h * 136 + 32 * ks + 8 * lg];
#pragma unroll
        for (int df = 0; df < 8; df++) {
#pragma unroll
            for (int ks = 0; ks < 4; ks++) {
                bf16x8 vf = *(const bf16x8*)&Vts[(16 * df + l15) * 136 + 32 * ks + 8 * lg];
                accO[df] = __builtin_amdgcn_mfma_f32_16x16x32_bf16(vf, pf[ks], accO[df], 0, 0, 0);
            }
        }
        __syncthreads();
    }
    const size_t base = ((size_t)(b * 2 + split)) * 16384 + (size_t)h * 128;
#pragma unroll
    for (int df = 0; df < 8; df++)
        *(f32x4*)&Opart[base + 16 * df + 4 * lg] = accO[df];
    if (lg == 0) {
        m_ws[(b * 2 + split) * 128 + h] = m_run;
        l_ws[(b * 2 + split) * 128 + h] = l_run;
    }
}

// ---------------------------------------------------------------------------
__global__ __launch_bounds__(256)
void combine2(const float* __restrict__ Opart, const float* __restrict__ m_ws,
              const float* __restrict__ l_ws, float* __restrict__ attn)
{
    const int idx = blockIdx.x * 256 + threadIdx.x;
    const int d4 = (idx & 31) * 4;
    const int hh = (idx >> 5) & 127;
    const int b = idx >> 12;
    const float m1 = m_ws[(b * 2) * 128 + hh], m2 = m_ws[(b * 2 + 1) * 128 + hh];
    const float l1 = l_ws[(b * 2) * 128 + hh], l2 = l_ws[(b * 2 + 1) * 128 + hh];
    const float m = fmaxf(m1, m2);
    const float a1 = (l1 > 0.f) ? __expf(m1 - m) : 0.f;
    const float a2 = (l2 > 0.f) ? __expf(m2 - m) : 0.f;
    const float inv = 1.0f / (a1 * l1 + a2 * l2);
    f32x4 o1 = *(const f32x4*)&Opart[((size_t)(b * 2)) * 16384 + (size_t)hh * 128 + d4];
    f32x4 o2 = *(const f32x4*)&Opart[((size_t)(b * 2 + 1)) * 16384 + (size_t)hh * 128 + d4];
    f32x4 r = (o1 * a1 + o2 * a2) * inv;
    *(f32x4*)&attn[(size_t)b * 16384 + (size_t)hh * 128 + d4] = r;
}

// ---------------------------------------------------------------------------
extern "C" void kernel_launch(void* const* d_in, const int* in_sizes, int n_in,
                              void* d_out, int out_size, void* d_ws, size_t ws_size,
                              hipStream_t stream)
{
    const float* hidden  = (const float*)d_in[0];
    const float* k_cache = (const float*)d_in[1];
    const float* v_cache = (const float*)d_in[2];
    const float* Wq      = (const float*)d_in[3];
    const float* Wkv     = (const float*)d_in[4];
    const float* Wo      = (const float*)d_in[5];
    const int* slot_map  = (const int*)d_in[7];
    const int* seq_lens  = (const int*)d_in[8];
    float* out = (float*)d_out;

    float* ws      = (float*)d_ws;
    float* q_ws    = ws;                 // 2,097,152 f
    float* attn_ws = ws + 2097152;       // 2,097,152 f
    float* kv_ws   = ws + 4194304;       //    32,768 f
    float* Opart   = ws + 4227072;       // 4,194,304 f
    float* m_ws    = ws + 8421376;       //    32,768 f
    float* l_ws    = ws + 8454144;       //    32,768 f

    hipMemsetAsync(kv_ws, 0, 32768 * sizeof(float), stream);
    hipMemsetAsync(q_ws, 0, 2097152 * sizeof(float), stream);
    hipMemsetAsync(d_out, 0, (size_t)out_size * sizeof(float), stream);

    // kv = hidden @ Wkv[:, :256]   (K-split 16)
    gemm128<<<dim3(4 * 16), 256, 0, stream>>>(hidden, 5120, Wkv, 576, kv_ws, 256, 320, 16, 0, 1);
    // q_nope = hidden @ Wq (nope cols; K-split 4)
    gemm128<<<dim3(256 * 4), 256, 0, stream>>>(hidden, 5120, Wq, 24576, q_ws, 16384, 1280, 4, 1, 1);
    // attention (2 S-splits per batch)
    attn_fwd<<<dim3(128, 2), 512, 0, stream>>>(k_cache, v_cache, q_ws, kv_ws,
                                               seq_lens, slot_map, Opart, m_ws, l_ws);
    combine2<<<dim3(2048), 256, 0, stream>>>(Opart, m_ws, l_ws, attn_ws);
    // out = attn @ Wo   (K-split 8)
    gemm128<<<dim3(80 * 8), 256, 0, stream>>>(attn_ws, 16384, Wo, 5120, out, 5120, 2048, 8, 0, 1);
}

// Round 3
// 391.145 us; speedup vs baseline: 1.9798x; 1.1289x over previous
//
#include <hip/hip_runtime.h>

typedef __attribute__((ext_vector_type(4))) float f32x4;
typedef __attribute__((ext_vector_type(8))) short bf16x8;
typedef __attribute__((ext_vector_type(2))) unsigned int u32x2;
typedef __attribute__((ext_vector_type(4))) unsigned int u32x4;

static __device__ __forceinline__ unsigned short f2bf(float f) {
    unsigned u = __builtin_bit_cast(unsigned, f);
    u += 0x7fffu + ((u >> 16) & 1u);   // RNE
    return (unsigned short)(u >> 16);
}
static __device__ __forceinline__ unsigned pack2(float a, float b) {
    return (unsigned)f2bf(a) | ((unsigned)f2bf(b) << 16);
}

// ---------------------------------------------------------------------------
// C_partial[by][128 x N] = A[128 x Kslice(fp32)] * B[Kslice x N(fp32)].
// bf16 MFMA, fp32 accum, register-prefetch double buffering, NO atomics.
// 1D grid = ntiles * nsplit; bx = blockIdx.x / nsplit, by = blockIdx.x % nsplit.
// ---------------------------------------------------------------------------
__global__ __launch_bounds__(256, 3)
void gemm128(const float* __restrict__ A, int lda,
             const float* __restrict__ Bm, int ldb,
             float* __restrict__ Cp, int ldc,
             int kchunk, int nsplit, int colmap)
{
    __shared__ __align__(16) unsigned short As[128 * 72];
    __shared__ __align__(16) unsigned short Bs[64 * 66];   // stride 33 dwords

    const int tid = threadIdx.x;
    const int w = tid >> 6, l = tid & 63, lg = l >> 4, l15 = l & 15;
    const int bx = blockIdx.x / nsplit;
    const int by = blockIdx.x % nsplit;
    const int n0 = bx * 64;
    const int pcol = colmap ? ((n0 >> 7) * 192 + (n0 & 127)) : n0;
    const size_t k0base = (size_t)by * (size_t)kchunk;
    float* __restrict__ C = Cp + (size_t)by * ((size_t)128 * (size_t)ldc);

    const int ac4 = (tid & 15) * 4;   // A col within tile
    const int ar  = tid >> 4;         // A row base
    const int bnb = (tid & 15) * 4;   // B col within tile
    const int bkk = tid >> 4;         // B k-pair base

    f32x4 aReg[8];
    f32x4 bReg[2][2];

    auto loadTiles = [&](size_t k0) {
#pragma unroll
        for (int j = 0; j < 8; j++)
            aReg[j] = *(const f32x4*)(A + (size_t)(ar + 16 * j) * lda + k0 + ac4);
#pragma unroll
        for (int i = 0; i < 2; i++) {
            const float* bp = Bm + (k0 + (size_t)(2 * (bkk + 16 * i))) * (size_t)ldb + pcol + bnb;
            bReg[i][0] = *(const f32x4*)bp;
            bReg[i][1] = *(const f32x4*)(bp + ldb);
        }
    };
    auto storeTiles = [&]() {
#pragma unroll
        for (int j = 0; j < 8; j++) {
            u32x2 wv = { pack2(aReg[j][0], aReg[j][1]), pack2(aReg[j][2], aReg[j][3]) };
            *(u32x2*)&As[(ar + 16 * j) * 72 + ac4] = wv;
        }
        unsigned* bd = (unsigned*)Bs;
#pragma unroll
        for (int i = 0; i < 2; i++)
#pragma unroll
            for (int j = 0; j < 4; j++)
                bd[(bnb + j) * 33 + bkk + 16 * i] = pack2(bReg[i][0][j], bReg[i][1][j]);
    };

    f32x4 acc[2][4];
    const f32x4 fzero = {0.f, 0.f, 0.f, 0.f};
#pragma unroll
    for (int a = 0; a < 2; a++)
#pragma unroll
        for (int b2 = 0; b2 < 4; b2++) acc[a][b2] = fzero;

    loadTiles(k0base);
    for (int kt = 0; kt < kchunk; kt += 64) {
        storeTiles();
        __syncthreads();
        if (kt + 64 < kchunk) loadTiles(k0base + (size_t)kt + 64);
        __builtin_amdgcn_sched_barrier(0);   // pin prefetch: do not sink loads
#pragma unroll
        for (int ks = 0; ks < 2; ks++) {
            bf16x8 bfr[4];
#pragma unroll
            for (int nf = 0; nf < 4; nf++)
                bfr[nf] = *(const bf16x8*)&Bs[(16 * nf + l15) * 66 + 32 * ks + 8 * lg];
#pragma unroll
            for (int mf = 0; mf < 2; mf++) {
                bf16x8 af = *(const bf16x8*)&As[(32 * w + 16 * mf + l15) * 72 + 32 * ks + 8 * lg];
#pragma unroll
                for (int nf = 0; nf < 4; nf++)
                    acc[mf][nf] = __builtin_amdgcn_mfma_f32_16x16x32_bf16(af, bfr[nf], acc[mf][nf], 0, 0, 0);
            }
        }
        __syncthreads();
    }
#pragma unroll
    for (int mf = 0; mf < 2; mf++) {
#pragma unroll
        for (int nf = 0; nf < 4; nf++) {
            const int m0 = 32 * w + 16 * mf + 4 * lg;
            const int cn = n0 + 16 * nf + l15;
#pragma unroll
            for (int r = 0; r < 4; r++)
                C[(size_t)(m0 + r) * ldc + cn] = acc[mf][nf][r];
        }
    }
}

// ---------------------------------------------------------------------------
// reduce ns partial buffers of n4*4 floats each: out = sum_j in[.. + j*n4*4]
// ---------------------------------------------------------------------------
__global__ __launch_bounds__(256)
void reduce_f32(const float* __restrict__ in, float* __restrict__ out, int n4, int ns)
{
    const int i = blockIdx.x * 256 + threadIdx.x;
    if (i >= n4) return;
    const f32x4* in4 = (const f32x4*)in;
    f32x4 s = in4[i];
    for (int j = 1; j < ns; j++) s += in4[i + (size_t)j * n4];
    ((f32x4*)out)[i] = s;
}

// ---------------------------------------------------------------------------
// reduce 4 q partials, fold softmax scale, pack to bf16.
// ---------------------------------------------------------------------------
__global__ __launch_bounds__(256)
void reduce_q_bf16(const float* __restrict__ in, unsigned* __restrict__ out)
{
    const int i = blockIdx.x * 256 + threadIdx.x;   // 0..524287 (f32x4 units)
    const f32x4* in4 = (const f32x4*)in;
    f32x4 s = in4[i] + in4[i + 524288] + in4[i + 2 * 524288] + in4[i + 3 * 524288];
    const float scale = 0.088388347648318447f;      // 1/sqrt(128)
    s *= scale;
    u32x2 p = { pack2(s[0], s[1]), pack2(s[2], s[3]) };
    *(u32x2*)&out[2 * i] = p;
}

// ---------------------------------------------------------------------------
// Flash-decode attention, chunked S-splits for load balance.
// grid = (B, NSPLIT=8); split s owns K-tiles [4s, 4s+4) ∩ [0, nt).
// block = 512 (8 waves); wave w owns heads 16w..16w+15. Swapped QK^T.
// Q input is bf16 with scale pre-folded.
// ---------------------------------------------------------------------------
#define NSPLIT 8
#define CHUNK_T 4

__global__ __launch_bounds__(512)
void attn_fwd(const float* __restrict__ kc, const float* __restrict__ vc,
              const unsigned short* __restrict__ qb, const float* __restrict__ kvws,
              const int* __restrict__ seq_lens, const int* __restrict__ slot_map,
              float* __restrict__ Opart, float* __restrict__ m_ws, float* __restrict__ l_ws)
{
    __shared__ __align__(16) unsigned short Ks [128 * 136];
    __shared__ __align__(16) unsigned short Vts[128 * 136];
    __shared__ __align__(16) unsigned short Ps [128 * 136];

    const int b = blockIdx.x, split = blockIdx.y;
    const int seq = seq_lens[b], slot = slot_map[b];
    const int nt = (seq + 127) >> 7;
    const int t0 = split * CHUNK_T;
    const int t1 = min(t0 + CHUNK_T, nt);

    const int tid = threadIdx.x, w = tid >> 6, l = tid & 63, lg = l >> 4, l15 = l & 15;
    const int h = 16 * w + l15;

    float m_run = -__builtin_inff(), l_run = 0.0f;

    if (t0 < t1) {
        const float* knew = kvws + b * 256;
        const float* vnew = knew + 128;

        // Q fragments: bf16, pre-scaled
        bf16x8 qf[4];
        {
            const unsigned short* qrow = qb + (size_t)b * 16384 + (size_t)h * 128;
#pragma unroll
            for (int ks = 0; ks < 4; ks++)
                qf[ks] = *(const bf16x8*)(qrow + 32 * ks + 8 * lg);
        }

        // staging register slots
        f32x4 kReg[2][4];
        f32x4 vReg[4][2];
        const int kr  = tid >> 3;
        const int kcb = (tid & 7) * 16;
        const int vd4 = (tid & 31) * 4;
        const int vsp = tid >> 5;

        auto loadKV = [&](int t) {
            const int s0 = t << 7;
#pragma unroll
            for (int pass = 0; pass < 2; ++pass) {
                const int s = s0 + kr + 64 * pass;
                const float* src = (s == slot) ? knew : (kc + ((size_t)b * 4096 + s) * 128);
                kReg[pass][0] = *(const f32x4*)(src + kcb);
                kReg[pass][1] = *(const f32x4*)(src + kcb + 4);
                kReg[pass][2] = *(const f32x4*)(src + kcb + 8);
                kReg[pass][3] = *(const f32x4*)(src + kcb + 12);
            }
#pragma unroll
            for (int i = 0; i < 4; i++) {
                const int sp = vsp + 16 * i;
                const int s1 = s0 + 2 * sp, s2 = s1 + 1;
                const float* r1 = (s1 == slot) ? vnew : (vc + ((size_t)b * 4096 + s1) * 128);
                const float* r2 = (s2 == slot) ? vnew : (vc + ((size_t)b * 4096 + s2) * 128);
                vReg[i][0] = *(const f32x4*)(r1 + vd4);
                vReg[i][1] = *(const f32x4*)(r2 + vd4);
            }
        };
        auto storeKV = [&]() {
#pragma unroll
            for (int pass = 0; pass < 2; ++pass) {
                const int rr = kr + 64 * pass;
                u32x4 w0 = { pack2(kReg[pass][0][0], kReg[pass][0][1]), pack2(kReg[pass][0][2], kReg[pass][0][3]),
                             pack2(kReg[pass][1][0], kReg[pass][1][1]), pack2(kReg[pass][1][2], kReg[pass][1][3]) };
                u32x4 w1 = { pack2(kReg[pass][2][0], kReg[pass][2][1]), pack2(kReg[pass][2][2], kReg[pass][2][3]),
                             pack2(kReg[pass][3][0], kReg[pass][3][1]), pack2(kReg[pass][3][2], kReg[pass][3][3]) };
                *(u32x4*)&Ks[rr * 136 + kcb] = w0;
                *(u32x4*)&Ks[rr * 136 + kcb + 8] = w1;
            }
            unsigned* vt = (unsigned*)Vts;
#pragma unroll
            for (int i = 0; i < 4; i++) {
                const int sp = vsp + 16 * i;
#pragma unroll
                for (int j = 0; j < 4; j++)
                    vt[(vd4 + j) * 68 + sp] = pack2(vReg[i][0][j], vReg[i][1][j]);
            }
        };

        f32x4 accO[8];
        const f32x4 fzero = {0.f, 0.f, 0.f, 0.f};
#pragma unroll
        for (int i = 0; i < 8; i++) accO[i] = fzero;

        loadKV(t0);
        for (int t = t0; t < t1; ++t) {
            const int s0 = t << 7;
            storeKV();
            __syncthreads();
            if (t + 1 < t1) loadKV(t + 1);
            __builtin_amdgcn_sched_barrier(0);   // pin prefetch

            // ---- scores^T = K * Q^T
            f32x4 accS[8];
#pragma unroll
            for (int sf = 0; sf < 8; sf++) accS[sf] = fzero;
#pragma unroll
            for (int ks = 0; ks < 4; ks++) {
#pragma unroll
                for (int sf = 0; sf < 8; sf++) {
                    bf16x8 kf = *(const bf16x8*)&Ks[(16 * sf + l15) * 136 + 32 * ks + 8 * lg];
                    accS[sf] = __builtin_amdgcn_mfma_f32_16x16x32_bf16(kf, qf[ks], accS[sf], 0, 0, 0);
                }
            }
            // ---- mask + online softmax (lane's s = s0 + 16*sf + 4*lg + r)
            float tmax = -__builtin_inff();
#pragma unroll
            for (int sf = 0; sf < 8; sf++) {
#pragma unroll
                for (int r = 0; r < 4; r++) {
                    const int s = s0 + 16 * sf + 4 * lg + r;
                    float sc = (s < seq) ? accS[sf][r] : -__builtin_inff();
                    accS[sf][r] = sc;
                    tmax = fmaxf(tmax, sc);
                }
            }
            tmax = fmaxf(tmax, __shfl_xor(tmax, 16));
            tmax = fmaxf(tmax, __shfl_xor(tmax, 32));
            const float mnew = fmaxf(m_run, tmax);
            const float so = __expf(m_run - mnew);
            float lsum = 0.f;
#pragma unroll
            for (int sf = 0; sf < 8; sf++) {
#pragma unroll
                for (int r = 0; r < 4; r++) {
                    const float p = __expf(accS[sf][r] - mnew);  // exp(-inf)=0 masks
                    accS[sf][r] = p;
                    lsum += p;
                }
            }
            lsum += __shfl_xor(lsum, 16);
            lsum += __shfl_xor(lsum, 32);
            l_run = l_run * so + lsum;
            m_run = mnew;
#pragma unroll
            for (int i = 0; i < 8; i++) accO[i] *= so;

            // ---- P -> LDS (wave-private rows)
            {
                unsigned* pd = (unsigned*)Ps;
#pragma unroll
                for (int sf = 0; sf < 8; sf++) {
                    pd[h * 68 + 8 * sf + 2 * lg + 0] = pack2(accS[sf][0], accS[sf][1]);
                    pd[h * 68 + 8 * sf + 2 * lg + 1] = pack2(accS[sf][2], accS[sf][3]);
                }
            }
            // ---- O^T += V^T * P^T
            bf16x8 pf[4];
#pragma unroll
            for (int ks = 0; ks < 4; ks++)
                pf[ks] = *(const bf16x8*)&Ps[h * 136 + 32 * ks + 8 * lg];
#pragma unroll
            for (int df = 0; df < 8; df++) {
#pragma unroll
                for (int ks = 0; ks < 4; ks++) {
                    bf16x8 vf = *(const bf16x8*)&Vts[(16 * df + l15) * 136 + 32 * ks + 8 * lg];
                    accO[df] = __builtin_amdgcn_mfma_f32_16x16x32_bf16(vf, pf[ks], accO[df], 0, 0, 0);
                }
            }
            __syncthreads();
        }
        const size_t base = ((size_t)(b * NSPLIT + split)) * 16384 + (size_t)h * 128;
#pragma unroll
        for (int df = 0; df < 8; df++)
            *(f32x4*)&Opart[base + 16 * df + 4 * lg] = accO[df];
    }
    if (lg == 0) {
        m_ws[(b * NSPLIT + split) * 128 + h] = m_run;
        l_ws[(b * NSPLIT + split) * 128 + h] = l_run;
    }
}

// ---------------------------------------------------------------------------
// Combine the 8 S-split partials.
// ---------------------------------------------------------------------------
__global__ __launch_bounds__(256)
void combine8(const float* __restrict__ Opart, const float* __restrict__ m_ws,
              const float* __restrict__ l_ws, float* __restrict__ attn)
{
    const int idx = blockIdx.x * 256 + threadIdx.x;  // 0..524287
    const int d4 = (idx & 31) * 4;
    const int hh = (idx >> 5) & 127;
    const int b = idx >> 12;

    float m = -__builtin_inff();
    float mv[NSPLIT], lv[NSPLIT];
#pragma unroll
    for (int j = 0; j < NSPLIT; j++) {
        mv[j] = m_ws[(b * NSPLIT + j) * 128 + hh];
        lv[j] = l_ws[(b * NSPLIT + j) * 128 + hh];
        m = fmaxf(m, mv[j]);
    }
    f32x4 o = {0.f, 0.f, 0.f, 0.f};
    float lsum = 0.f;
#pragma unroll
    for (int j = 0; j < NSPLIT; j++) {
        const float a = (lv[j] > 0.f) ? __expf(mv[j] - m) : 0.f;
        lsum += a * lv[j];
        if (a > 0.f) {
            f32x4 oj = *(const f32x4*)&Opart[((size_t)(b * NSPLIT + j)) * 16384 + (size_t)hh * 128 + d4];
            o += oj * a;
        }
    }
    o *= (1.0f / lsum);
    *(f32x4*)&attn[(size_t)b * 16384 + (size_t)hh * 128 + d4] = o;
}

// ---------------------------------------------------------------------------
extern "C" void kernel_launch(void* const* d_in, const int* in_sizes, int n_in,
                              void* d_out, int out_size, void* d_ws, size_t ws_size,
                              hipStream_t stream)
{
    const float* hidden  = (const float*)d_in[0];
    const float* k_cache = (const float*)d_in[1];
    const float* v_cache = (const float*)d_in[2];
    const float* Wq      = (const float*)d_in[3];
    const float* Wkv     = (const float*)d_in[4];
    const float* Wo      = (const float*)d_in[5];
    const int* slot_map  = (const int*)d_in[7];
    const int* seq_lens  = (const int*)d_in[8];
    float* out = (float*)d_out;

    float* ws      = (float*)d_ws;
    float* qp      = ws;                  // 4 x 2,097,152        =  8,388,608 f
    float* qb      = ws + 8388608;        // bf16 2,097,152       =    524,288 f
    float* kvp     = ws + 8912896;        // 16 x 32,768          =    524,288 f
    float* kv_ws   = ws + 9437184;        //                      =     32,768 f
    float* attn_ws = ws + 9469952;        //                      =  2,097,152 f
    float* Opart   = ws + 11567104;       // 128*8*16384          = 16,777,216 f
    float* m_ws    = ws + 28344320;       //                      =    131,072 f
    float* l_ws    = ws + 28475392;       //                      =    131,072 f
    float* outp    = ws + 28606464;       // 8 x 655,360          =  5,242,880 f

    // kv partials = hidden @ Wkv[:, :256]   (K-split 16)
    gemm128<<<dim3(4 * 16), 256, 0, stream>>>(hidden, 5120, Wkv, 576, kvp, 256, 320, 16, 0);
    // q partials = hidden @ Wq (nope cols; K-split 4)
    gemm128<<<dim3(256 * 4), 256, 0, stream>>>(hidden, 5120, Wq, 24576, qp, 16384, 1280, 4, 1);
    // reduce kv (fp32) and q (scaled bf16)
    reduce_f32<<<dim3(32), 256, 0, stream>>>(kvp, kv_ws, 8192, 16);
    reduce_q_bf16<<<dim3(2048), 256, 0, stream>>>(qp, (unsigned*)qb);
    // attention (8 chunked S-splits per batch)
    attn_fwd<<<dim3(128, NSPLIT), 512, 0, stream>>>(k_cache, v_cache, (const unsigned short*)qb,
                                                    kv_ws, seq_lens, slot_map, Opart, m_ws, l_ws);
    combine8<<<dim3(2048), 256, 0, stream>>>(Opart, m_ws, l_ws, attn_ws);
    // out partials = attn @ Wo   (K-split 8)
    gemm128<<<dim3(80 * 8), 256, 0, stream>>>(attn_ws, 16384, Wo, 5120, outp, 5120, 2048, 8, 0);
    reduce_f32<<<dim3(640), 256, 0, stream>>>(outp, out, 163840, 8);
}

// Round 4
// 369.221 us; speedup vs baseline: 2.0974x; 1.0594x over previous
//
#include <hip/hip_runtime.h>

typedef __attribute__((ext_vector_type(4))) float f32x4;
typedef __attribute__((ext_vector_type(8))) short bf16x8;
typedef __attribute__((ext_vector_type(2))) unsigned int u32x2;
typedef __attribute__((ext_vector_type(4))) unsigned int u32x4;

static __device__ __forceinline__ unsigned short f2bf(float f) {
    unsigned u = __builtin_bit_cast(unsigned, f);
    u += 0x7fffu + ((u >> 16) & 1u);   // RNE
    return (unsigned short)(u >> 16);
}
static __device__ __forceinline__ unsigned pack2(float a, float b) {
    return (unsigned)f2bf(a) | ((unsigned)f2bf(b) << 16);
}

// ---------------------------------------------------------------------------
// C_partial[by][128 x N] = A[128 x Kslice] * B[Kslice x N(fp32)].
// ABF16: A is bf16 (lda in ushorts) else fp32. bf16 MFMA, fp32 accum.
// 2-deep B register prefetch (counted vmcnt), 1-deep A. No atomics.
// grid 1D = ntiles*nsplit; bx = blockIdx.x/nsplit, by = blockIdx.x%nsplit.
// ---------------------------------------------------------------------------
template<int ABF16, int COLMAP>
__global__ __launch_bounds__(256, 4)
void gemm128(const void* __restrict__ A_, int lda,
             const float* __restrict__ Bm, int ldb,
             float* __restrict__ Cp, int ldc,
             int kchunk, int nsplit)
{
    __shared__ __align__(16) unsigned short As[128 * 72];
    __shared__ __align__(16) unsigned short Bs[64 * 66];   // 33-dword stride

    const int tid = threadIdx.x;
    const int w = tid >> 6, l = tid & 63, lg = l >> 4, l15 = l & 15;
    const int bx = blockIdx.x / nsplit;
    const int by = blockIdx.x % nsplit;
    const int n0 = bx * 64;
    const int pcol = COLMAP ? ((n0 >> 7) * 192 + (n0 & 127)) : n0;
    const size_t k0base = (size_t)by * (size_t)kchunk;
    float* __restrict__ C = Cp + (size_t)by * ((size_t)128 * (size_t)ldc);

    // fp32-A mapping: row = (tid>>3) + 32j, 8 floats at (tid&7)*8
    const int ar  = tid >> 3;
    const int ac8 = (tid & 7) * 8;
    // bf16-A mapping: row = tid>>1, 32 ushorts at (tid&1)*32
    const int br  = tid >> 1;
    const int bc  = (tid & 1) * 32;
    // B mapping
    const int bnb = (tid & 15) * 4;
    const int bkk = tid >> 4;

    f32x4 aReg[4][2];
    u32x4 aRegH[4];
    f32x4 b0Reg[2][2], b1Reg[2][2];

    const float* Af = (const float*)A_;
    const unsigned short* Ah = (const unsigned short*)A_;

    auto loadA = [&](size_t k0) {
        if (ABF16) {
#pragma unroll
            for (int k = 0; k < 4; k++)
                aRegH[k] = *(const u32x4*)(Ah + (size_t)br * lda + k0 + bc + 8 * k);
        } else {
#pragma unroll
            for (int j = 0; j < 4; j++) {
                const float* p = Af + (size_t)(ar + 32 * j) * lda + k0 + ac8;
                aReg[j][0] = *(const f32x4*)p;
                aReg[j][1] = *(const f32x4*)(p + 4);
            }
        }
    };
    auto storeA = [&]() {
        if (ABF16) {
#pragma unroll
            for (int k = 0; k < 4; k++)
                *(u32x4*)&As[br * 72 + bc + 8 * k] = aRegH[k];
        } else {
#pragma unroll
            for (int j = 0; j < 4; j++) {
                u32x4 wv = { pack2(aReg[j][0][0], aReg[j][0][1]), pack2(aReg[j][0][2], aReg[j][0][3]),
                             pack2(aReg[j][1][0], aReg[j][1][1]), pack2(aReg[j][1][2], aReg[j][1][3]) };
                *(u32x4*)&As[(ar + 32 * j) * 72 + ac8] = wv;
            }
        }
    };
    auto loadB = [&](f32x4 (&bR)[2][2], size_t k0) {
#pragma unroll
        for (int i = 0; i < 2; i++) {
            const float* bp = Bm + (k0 + (size_t)(2 * (bkk + 16 * i))) * (size_t)ldb + pcol + bnb;
            bR[i][0] = *(const f32x4*)bp;
            bR[i][1] = *(const f32x4*)(bp + ldb);
        }
    };
    auto storeB = [&](f32x4 (&bR)[2][2]) {
        unsigned* bd = (unsigned*)Bs;
#pragma unroll
        for (int i = 0; i < 2; i++)
#pragma unroll
            for (int j = 0; j < 4; j++)
                bd[(bnb + j) * 33 + bkk + 16 * i] = pack2(bR[i][0][j], bR[i][1][j]);
    };

    f32x4 acc[2][4];
    const f32x4 fzero = {0.f, 0.f, 0.f, 0.f};
#pragma unroll
    for (int a = 0; a < 2; a++)
#pragma unroll
        for (int b2 = 0; b2 < 4; b2++) acc[a][b2] = fzero;

    auto mfmaStep = [&]() {
#pragma unroll
        for (int ks = 0; ks < 2; ks++) {
            bf16x8 bfr[4];
#pragma unroll
            for (int nf = 0; nf < 4; nf++)
                bfr[nf] = *(const bf16x8*)&Bs[(16 * nf + l15) * 66 + 32 * ks + 8 * lg];
#pragma unroll
            for (int mf = 0; mf < 2; mf++) {
                bf16x8 af = *(const bf16x8*)&As[(32 * w + 16 * mf + l15) * 72 + 32 * ks + 8 * lg];
#pragma unroll
                for (int nf = 0; nf < 4; nf++)
                    acc[mf][nf] = __builtin_amdgcn_mfma_f32_16x16x32_bf16(af, bfr[nf], acc[mf][nf], 0, 0, 0);
            }
        }
    };

    const int nst = kchunk >> 6;
    auto kof = [&](int t) { return k0base + (size_t)(t << 6); };

    loadA(kof(0));
    loadB(b0Reg, kof(0));
    if (nst > 1) loadB(b1Reg, kof(1));

    for (int t = 0; t < nst; t += 2) {
        // even step: consumes b0Reg
        storeA(); storeB(b0Reg);
        __syncthreads();
        if (t + 1 < nst) loadA(kof(t + 1));
        if (t + 2 < nst) loadB(b0Reg, kof(t + 2));
        __builtin_amdgcn_sched_barrier(0);
        mfmaStep();
        __syncthreads();
        // odd step: consumes b1Reg
        if (t + 1 < nst) {
            storeA(); storeB(b1Reg);
            __syncthreads();
            if (t + 2 < nst) loadA(kof(t + 2));
            if (t + 3 < nst) loadB(b1Reg, kof(t + 3));
            __builtin_amdgcn_sched_barrier(0);
            mfmaStep();
            __syncthreads();
        }
    }
#pragma unroll
    for (int mf = 0; mf < 2; mf++) {
#pragma unroll
        for (int nf = 0; nf < 4; nf++) {
            const int m0 = 32 * w + 16 * mf + 4 * lg;
            const int cn = n0 + 16 * nf + l15;
#pragma unroll
            for (int r = 0; r < 4; r++)
                C[(size_t)(m0 + r) * ldc + cn] = acc[mf][nf][r];
        }
    }
}

// ---------------------------------------------------------------------------
__global__ __launch_bounds__(256)
void reduce_f32(const float* __restrict__ in, float* __restrict__ out, int n4, int ns)
{
    const int i = blockIdx.x * 256 + threadIdx.x;
    if (i >= n4) return;
    const f32x4* in4 = (const f32x4*)in;
    f32x4 s = in4[i];
    for (int j = 1; j < ns; j++) s += in4[i + (size_t)j * n4];
    ((f32x4*)out)[i] = s;
}

// ---------------------------------------------------------------------------
// reduce 4 q partials, fold softmax scale, pack to bf16.
// ---------------------------------------------------------------------------
__global__ __launch_bounds__(256)
void reduce_q_bf16(const float* __restrict__ in, unsigned* __restrict__ out)
{
    const int i = blockIdx.x * 256 + threadIdx.x;   // f32x4 units
    const f32x4* in4 = (const f32x4*)in;
    f32x4 s = in4[i] + in4[i + 524288] + in4[i + 2 * 524288] + in4[i + 3 * 524288];
    const float scale = 0.088388347648318447f;      // 1/sqrt(128)
    s *= scale;
    u32x2 p = { pack2(s[0], s[1]), pack2(s[2], s[3]) };
    *(u32x2*)&out[2 * i] = p;
}

// ---------------------------------------------------------------------------
// Flash-decode attention. KVBLK=64, grid (B, NSPLIT=8), block 512 (8 waves).
// Split s owns K-tiles [8s, 8s+8) ∩ [0, nt), nt = ceil(seq/64).
// kv-reduce fused (8 partials); slot row patched post-staging.
// Swapped QK^T: mfma(K, Q); Q is pre-scaled bf16.
// ---------------------------------------------------------------------------
#define NSPLIT 8
#define CHUNK_T 8

__global__ __launch_bounds__(512, 4)
void attn_fwd(const float* __restrict__ kc, const float* __restrict__ vc,
              const unsigned short* __restrict__ qb, const float* __restrict__ kvp,
              const int* __restrict__ seq_lens, const int* __restrict__ slot_map,
              float* __restrict__ Opart, float* __restrict__ m_ws, float* __restrict__ l_ws)
{
    __shared__ __align__(16) unsigned short Ks [64 * 136];   // [s][d], 68-dword stride
    __shared__ __align__(16) unsigned short Vts[128 * 72];   // [d][s-pair], 36-dword stride
    __shared__ __align__(16) unsigned short Ps [128 * 72];   // [h][s-pair], 36-dword stride
    __shared__ float knew_s[128];
    __shared__ float vnew_s[128];

    const int b = blockIdx.x, split = blockIdx.y;
    const int seq = seq_lens[b], slot = slot_map[b];
    const int nt = (seq + 63) >> 6;
    const int t0 = split * CHUNK_T;
    const int t1 = min(t0 + CHUNK_T, nt);
    const int slotTile = slot >> 6;

    const int tid = threadIdx.x, w = tid >> 6, l = tid & 63, lg = l >> 4, l15 = l & 15;
    const int h = 16 * w + l15;

    float m_run = -__builtin_inff(), l_run = 0.0f;

    if (t0 < t1) {
        // ---- fused kv reduction (needed only if slot row in range)
        if (slotTile >= t0 && slotTile < t1 && tid < 256) {
            float s = 0.f;
#pragma unroll
            for (int j = 0; j < 8; j++) s += kvp[j * 32768 + b * 256 + tid];
            if (tid < 128) knew_s[tid] = s;
            else           vnew_s[tid - 128] = s;
        }

        // ---- Q fragments (pre-scaled bf16)
        bf16x8 qf[4];
        {
            const unsigned short* qrow = qb + (size_t)b * 16384 + (size_t)h * 128;
#pragma unroll
            for (int ks = 0; ks < 4; ks++)
                qf[ks] = *(const bf16x8*)(qrow + 32 * ks + 8 * lg);
        }

        // ---- staging registers
        f32x4 kReg[4];
        f32x4 vReg[2][2];
        const int kr  = tid >> 3;           // 0..63 s-row
        const int kcb = (tid & 7) * 16;     // 16 floats
        const int vsp = tid & 31;           // s-pair 0..31
        const int vdq = tid >> 5;           // d-quad 0..15

        auto loadKV = [&](int t) {
            const int s0 = t << 6;
            const float* ksrc = kc + ((size_t)b * 4096 + s0 + kr) * 128 + kcb;
#pragma unroll
            for (int c = 0; c < 4; c++) kReg[c] = *(const f32x4*)(ksrc + 4 * c);
#pragma unroll
            for (int i = 0; i < 2; i++) {
                const int d4 = 4 * vdq + 64 * i;
                const float* r1 = vc + ((size_t)b * 4096 + s0 + 2 * vsp) * 128 + d4;
                vReg[i][0] = *(const f32x4*)r1;
                vReg[i][1] = *(const f32x4*)(r1 + 128);
            }
        };
        auto storeKV = [&]() {
            u32x4 w0 = { pack2(kReg[0][0], kReg[0][1]), pack2(kReg[0][2], kReg[0][3]),
                         pack2(kReg[1][0], kReg[1][1]), pack2(kReg[1][2], kReg[1][3]) };
            u32x4 w1 = { pack2(kReg[2][0], kReg[2][1]), pack2(kReg[2][2], kReg[2][3]),
                         pack2(kReg[3][0], kReg[3][1]), pack2(kReg[3][2], kReg[3][3]) };
            *(u32x4*)&Ks[kr * 136 + kcb] = w0;
            *(u32x4*)&Ks[kr * 136 + kcb + 8] = w1;
            unsigned* vt = (unsigned*)Vts;
#pragma unroll
            for (int i = 0; i < 2; i++)
#pragma unroll
                for (int j = 0; j < 4; j++)
                    vt[(4 * vdq + 64 * i + j) * 36 + vsp] = pack2(vReg[i][0][j], vReg[i][1][j]);
        };

        f32x4 accO[8];
        const f32x4 fzero = {0.f, 0.f, 0.f, 0.f};
#pragma unroll
        for (int i = 0; i < 8; i++) accO[i] = fzero;

        loadKV(t0);
        for (int t = t0; t < t1; ++t) {
            const int s0 = t << 6;
            storeKV();
            __syncthreads();
            if (t == slotTile) {              // block-uniform
                if (tid < 128) {
                    const int sloc = slot & 63;
                    Ks [sloc * 136 + tid] = f2bf(knew_s[tid]);
                    Vts[tid * 72 + sloc]  = f2bf(vnew_s[tid]);
                }
                __syncthreads();
            }
            if (t + 1 < t1) loadKV(t + 1);
            __builtin_amdgcn_sched_barrier(0);

            // ---- scores^T = K * Q^T
            f32x4 accS[4];
#pragma unroll
            for (int sf = 0; sf < 4; sf++) accS[sf] = fzero;
#pragma unroll
            for (int ks = 0; ks < 4; ks++) {
#pragma unroll
                for (int sf = 0; sf < 4; sf++) {
                    bf16x8 kf = *(const bf16x8*)&Ks[(16 * sf + l15) * 136 + 32 * ks + 8 * lg];
                    accS[sf] = __builtin_amdgcn_mfma_f32_16x16x32_bf16(kf, qf[ks], accS[sf], 0, 0, 0);
                }
            }
            // ---- mask + online softmax (lane's s = s0 + 16*sf + 4*lg + r)
            float tmax = -__builtin_inff();
#pragma unroll
            for (int sf = 0; sf < 4; sf++) {
#pragma unroll
                for (int r = 0; r < 4; r++) {
                    const int s = s0 + 16 * sf + 4 * lg + r;
                    float sc = (s < seq) ? accS[sf][r] : -__builtin_inff();
                    accS[sf][r] = sc;
                    tmax = fmaxf(tmax, sc);
                }
            }
            tmax = fmaxf(tmax, __shfl_xor(tmax, 16));
            tmax = fmaxf(tmax, __shfl_xor(tmax, 32));
            const float mnew = fmaxf(m_run, tmax);
            const float so = __expf(m_run - mnew);
            float lsum = 0.f;
#pragma unroll
            for (int sf = 0; sf < 4; sf++) {
#pragma unroll
                for (int r = 0; r < 4; r++) {
                    const float p = __expf(accS[sf][r] - mnew);
                    accS[sf][r] = p;
                    lsum += p;
                }
            }
            lsum += __shfl_xor(lsum, 16);
            lsum += __shfl_xor(lsum, 32);
            l_run = l_run * so + lsum;
            m_run = mnew;
#pragma unroll
            for (int i = 0; i < 8; i++) accO[i] *= so;

            // ---- P -> LDS (wave-private rows)
            {
                unsigned* pd = (unsigned*)Ps;
#pragma unroll
                for (int sf = 0; sf < 4; sf++) {
                    pd[h * 36 + 8 * sf + 2 * lg + 0] = pack2(accS[sf][0], accS[sf][1]);
                    pd[h * 36 + 8 * sf + 2 * lg + 1] = pack2(accS[sf][2], accS[sf][3]);
                }
            }
            // ---- O^T += V^T * P^T
            bf16x8 pf[2];
#pragma unroll
            for (int ks = 0; ks < 2; ks++)
                pf[ks] = *(const bf16x8*)&Ps[h * 72 + 32 * ks + 8 * lg];
#pragma unroll
            for (int df = 0; df < 8; df++) {
#pragma unroll
                for (int ks = 0; ks < 2; ks++) {
                    bf16x8 vf = *(const bf16x8*)&Vts[(16 * df + l15) * 72 + 32 * ks + 8 * lg];
                    accO[df] = __builtin_amdgcn_mfma_f32_16x16x32_bf16(vf, pf[ks], accO[df], 0, 0, 0);
                }
            }
            __syncthreads();
        }
        const size_t base = ((size_t)(b * NSPLIT + split)) * 16384 + (size_t)h * 128;
#pragma unroll
        for (int df = 0; df < 8; df++)
            *(f32x4*)&Opart[base + 16 * df + 4 * lg] = accO[df];
    }
    if (lg == 0) {
        m_ws[(b * NSPLIT + split) * 128 + h] = m_run;
        l_ws[(b * NSPLIT + split) * 128 + h] = l_run;
    }
}

// ---------------------------------------------------------------------------
// Combine the 8 S-split partials -> bf16 attn.
// ---------------------------------------------------------------------------
__global__ __launch_bounds__(256)
void combine8(const float* __restrict__ Opart, const float* __restrict__ m_ws,
              const float* __restrict__ l_ws, unsigned* __restrict__ attn_bf)
{
    const int idx = blockIdx.x * 256 + threadIdx.x;  // 0..524287
    const int d4 = (idx & 31) * 4;
    const int hh = (idx >> 5) & 127;
    const int b = idx >> 12;

    float m = -__builtin_inff();
    float mv[NSPLIT], lv[NSPLIT];
#pragma unroll
    for (int j = 0; j < NSPLIT; j++) {
        mv[j] = m_ws[(b * NSPLIT + j) * 128 + hh];
        lv[j] = l_ws[(b * NSPLIT + j) * 128 + hh];
        m = fmaxf(m, mv[j]);
    }
    f32x4 o = {0.f, 0.f, 0.f, 0.f};
    float lsum = 0.f;
#pragma unroll
    for (int j = 0; j < NSPLIT; j++) {
        const float a = (lv[j] > 0.f) ? __expf(mv[j] - m) : 0.f;
        lsum += a * lv[j];
        if (a > 0.f) {
            f32x4 oj = *(const f32x4*)&Opart[((size_t)(b * NSPLIT + j)) * 16384 + (size_t)hh * 128 + d4];
            o += oj * a;
        }
    }
    o *= (1.0f / lsum);
    u32x2 p = { pack2(o[0], o[1]), pack2(o[2], o[3]) };
    *(u32x2*)&attn_bf[(size_t)b * 8192 + (size_t)hh * 64 + (d4 >> 1)] = p;
}

// ---------------------------------------------------------------------------
extern "C" void kernel_launch(void* const* d_in, const int* in_sizes, int n_in,
                              void* d_out, int out_size, void* d_ws, size_t ws_size,
                              hipStream_t stream)
{
    const float* hidden  = (const float*)d_in[0];
    const float* k_cache = (const float*)d_in[1];
    const float* v_cache = (const float*)d_in[2];
    const float* Wq      = (const float*)d_in[3];
    const float* Wkv     = (const float*)d_in[4];
    const float* Wo      = (const float*)d_in[5];
    const int* slot_map  = (const int*)d_in[7];
    const int* seq_lens  = (const int*)d_in[8];
    float* out = (float*)d_out;

    float* ws      = (float*)d_ws;
    float* qp      = ws;                   //  8,388,608 f (4 splits)
    float* qb      = ws + 8388608;         //  1,048,576 f (bf16 2M)
    float* kvp     = ws + 9437184;         //    262,144 f (8 splits)
    float* attn_bf = ws + 9699328;         //  1,048,576 f (bf16 2M)
    float* Opart   = ws + 10747904;        // 16,777,216 f
    float* m_ws    = ws + 27525120;        //    131,072 f
    float* l_ws    = ws + 27656192;        //    131,072 f
    float* outp    = ws + 27787264;        //  5,242,880 f

    // kv partials = hidden @ Wkv[:, :256]   (K-split 8, 640 each)
    gemm128<0, 0><<<dim3(4 * 8), 256, 0, stream>>>(hidden, 5120, Wkv, 576, kvp, 256, 640, 8);
    // q partials = hidden @ Wq (nope cols; K-split 4, 1280 each)
    gemm128<0, 1><<<dim3(256 * 4), 256, 0, stream>>>(hidden, 5120, Wq, 24576, qp, 16384, 1280, 4);
    // q reduce -> scaled bf16
    reduce_q_bf16<<<dim3(2048), 256, 0, stream>>>(qp, (unsigned*)qb);
    // attention (8 chunked S-splits per batch; kv-reduce fused)
    attn_fwd<<<dim3(128, NSPLIT), 512, 0, stream>>>(k_cache, v_cache, (const unsigned short*)qb,
                                                    kvp, seq_lens, slot_map, Opart, m_ws, l_ws);
    combine8<<<dim3(2048), 256, 0, stream>>>(Opart, m_ws, l_ws, (unsigned*)attn_bf);
    // out partials = attn(bf16) @ Wo   (K-split 8, 2048 each)
    gemm128<1, 0><<<dim3(80 * 8), 256, 0, stream>>>(attn_bf, 16384, Wo, 5120, outp, 5120, 2048, 8);
    reduce_f32<<<dim3(640), 256, 0, stream>>>(outp, out, 163840, 8);
}

// Round 6
// 322.108 us; speedup vs baseline: 2.4041x; 1.1463x over previous
//
#include <hip/hip_runtime.h>
#include <hip/hip_bf16.h>

typedef __attribute__((ext_vector_type(4))) float f32x4;
typedef __attribute__((ext_vector_type(8))) short bf16x8;
typedef __attribute__((ext_vector_type(2))) unsigned int u32x2;
typedef __attribute__((ext_vector_type(4))) unsigned int u32x4;

static __device__ __forceinline__ unsigned short f2bf(float f) {
    unsigned u = __builtin_bit_cast(unsigned, f);
    u += 0x7fffu + ((u >> 16) & 1u);   // RNE
    return (unsigned short)(u >> 16);
}
static __device__ __forceinline__ unsigned pack2(float a, float b) {
    __hip_bfloat162 h = __float22bfloat162_rn(make_float2(a, b));  // v_cvt_pk_bf16_f32
    unsigned u;
    __builtin_memcpy(&u, &h, 4);
    return u;
}

// Barrier WITHOUT vmcnt drain: flush own LDS ops, raw s_barrier, pin scheduler.
// (__syncthreads would emit s_waitcnt vmcnt(0) and kill cross-barrier prefetch.)
static __device__ __forceinline__ void bar_nodrain() {
    __builtin_amdgcn_sched_barrier(0);
    asm volatile("s_waitcnt lgkmcnt(0)" ::: "memory");
    __builtin_amdgcn_s_barrier();
    __builtin_amdgcn_sched_barrier(0);
}

// ---------------------------------------------------------------------------
// hidden fp32 -> bf16 (row-major copy)
// ---------------------------------------------------------------------------
__global__ __launch_bounds__(256)
void cvt_bf16(const float* __restrict__ in, unsigned* __restrict__ out, int n8)
{
    const int i = blockIdx.x * 256 + threadIdx.x;
    if (i >= n8) return;
    f32x4 a = ((const f32x4*)in)[2 * i];
    f32x4 b = ((const f32x4*)in)[2 * i + 1];
    u32x4 p = { pack2(a[0], a[1]), pack2(a[2], a[3]), pack2(b[0], b[1]), pack2(b[2], b[3]) };
    ((u32x4*)out)[i] = p;
}

// ---------------------------------------------------------------------------
// C_partial[by][128 x N] = A_bf16[128 x Kslice] * B[Kslice x N(fp32)].
// bf16 MFMA, fp32 accum. Raw barriers (no vmcnt drain) + reg prefetch:
// A 1 step ahead, B 2 steps ahead -> counted vmcnt at the ds_writes.
// grid 1D = ntiles*nsplit; bx = blockIdx.x/nsplit, by = blockIdx.x%nsplit.
// ---------------------------------------------------------------------------
template<int COLMAP>
__global__ __launch_bounds__(256, 4)
void gemm128(const unsigned short* __restrict__ Ah, int lda,
             const float* __restrict__ Bm, int ldb,
             float* __restrict__ Cp, int ldc,
             int kchunk, int nsplit)
{
    __shared__ __align__(16) unsigned short As[128 * 72];
    __shared__ __align__(16) unsigned short Bs[64 * 66];   // 33-dword stride

    const int tid = threadIdx.x;
    const int w = tid >> 6, l = tid & 63, lg = l >> 4, l15 = l & 15;
    const int bx = blockIdx.x / nsplit;
    const int by = blockIdx.x % nsplit;
    const int n0 = bx * 64;
    const int pcol = COLMAP ? ((n0 >> 7) * 192 + (n0 & 127)) : n0;
    const size_t k0base = (size_t)by * (size_t)kchunk;
    float* __restrict__ C = Cp + (size_t)by * ((size_t)128 * (size_t)ldc);

    const int ar = tid >> 1;          // A row
    const int ac = (tid & 1) * 32;    // A col base (ushorts)
    const int bnb = (tid & 15) * 4;   // B col
    const int bkk = tid >> 4;         // B k-pair

    u32x4 aReg[4];
    f32x4 b0Reg[2][2], b1Reg[2][2];

    auto loadA = [&](size_t k0) {
#pragma unroll
        for (int k = 0; k < 4; k++)
            aReg[k] = *(const u32x4*)(Ah + (size_t)ar * lda + k0 + ac + 8 * k);
    };
    auto storeA = [&]() {
#pragma unroll
        for (int k = 0; k < 4; k++)
            *(u32x4*)&As[ar * 72 + ac + 8 * k] = aReg[k];
    };
    auto loadB = [&](f32x4 (&bR)[2][2], size_t k0) {
#pragma unroll
        for (int i = 0; i < 2; i++) {
            const float* bp = Bm + (k0 + (size_t)(2 * (bkk + 16 * i))) * (size_t)ldb + pcol + bnb;
            bR[i][0] = *(const f32x4*)bp;
            bR[i][1] = *(const f32x4*)(bp + ldb);
        }
    };
    auto storeB = [&](f32x4 (&bR)[2][2]) {
        unsigned* bd = (unsigned*)Bs;
#pragma unroll
        for (int i = 0; i < 2; i++)
#pragma unroll
            for (int j = 0; j < 4; j++)
                bd[(bnb + j) * 33 + bkk + 16 * i] = pack2(bR[i][0][j], bR[i][1][j]);
    };

    f32x4 acc[2][4];
    const f32x4 fzero = {0.f, 0.f, 0.f, 0.f};
#pragma unroll
    for (int a = 0; a < 2; a++)
#pragma unroll
        for (int b2 = 0; b2 < 4; b2++) acc[a][b2] = fzero;

    auto mfmaStep = [&]() {
#pragma unroll
        for (int ks = 0; ks < 2; ks++) {
            bf16x8 bfr[4];
#pragma unroll
            for (int nf = 0; nf < 4; nf++)
                bfr[nf] = *(const bf16x8*)&Bs[(16 * nf + l15) * 66 + 32 * ks + 8 * lg];
#pragma unroll
            for (int mf = 0; mf < 2; mf++) {
                bf16x8 af = *(const bf16x8*)&As[(32 * w + 16 * mf + l15) * 72 + 32 * ks + 8 * lg];
#pragma unroll
                for (int nf = 0; nf < 4; nf++)
                    acc[mf][nf] = __builtin_amdgcn_mfma_f32_16x16x32_bf16(af, bfr[nf], acc[mf][nf], 0, 0, 0);
            }
        }
    };

    const int nst = kchunk >> 6;
    auto kof = [&](int t) { return k0base + (size_t)(t << 6); };

    loadA(kof(0));
    loadB(b0Reg, kof(0));
    if (nst > 1) loadB(b1Reg, kof(1));

    for (int t = 0; t < nst; t += 2) {
        // even step: consumes aReg(t), b0Reg(t)
        storeA(); storeB(b0Reg);
        bar_nodrain();
        if (t + 1 < nst) loadA(kof(t + 1));
        if (t + 2 < nst) loadB(b0Reg, kof(t + 2));
        __builtin_amdgcn_sched_barrier(0);
        mfmaStep();
        bar_nodrain();
        // odd step: consumes aReg(t+1), b1Reg(t+1)
        if (t + 1 < nst) {
            storeA(); storeB(b1Reg);
            bar_nodrain();
            if (t + 2 < nst) loadA(kof(t + 2));
            if (t + 3 < nst) loadB(b1Reg, kof(t + 3));
            __builtin_amdgcn_sched_barrier(0);
            mfmaStep();
            bar_nodrain();
        }
    }
#pragma unroll
    for (int mf = 0; mf < 2; mf++) {
#pragma unroll
        for (int nf = 0; nf < 4; nf++) {
            const int m0 = 32 * w + 16 * mf + 4 * lg;
            const int cn = n0 + 16 * nf + l15;
#pragma unroll
            for (int r = 0; r < 4; r++)
                C[(size_t)(m0 + r) * ldc + cn] = acc[mf][nf][r];
        }
    }
}

// ---------------------------------------------------------------------------
__global__ __launch_bounds__(256)
void reduce_f32(const float* __restrict__ in, float* __restrict__ out, int n4, int ns)
{
    const int i = blockIdx.x * 256 + threadIdx.x;
    if (i >= n4) return;
    const f32x4* in4 = (const f32x4*)in;
    f32x4 s = in4[i];
    for (int j = 1; j < ns; j++) s += in4[i + (size_t)j * n4];
    ((f32x4*)out)[i] = s;
}

// ---------------------------------------------------------------------------
// reduce 4 q partials, fold softmax scale, pack to bf16.
// ---------------------------------------------------------------------------
__global__ __launch_bounds__(256)
void reduce_q_bf16(const float* __restrict__ in, unsigned* __restrict__ out)
{
    const int i = blockIdx.x * 256 + threadIdx.x;   // f32x4 units
    const f32x4* in4 = (const f32x4*)in;
    f32x4 s = in4[i] + in4[i + 524288] + in4[i + 2 * 524288] + in4[i + 3 * 524288];
    const float scale = 0.088388347648318447f;      // 1/sqrt(128)
    s *= scale;
    u32x2 p = { pack2(s[0], s[1]), pack2(s[2], s[3]) };
    *(u32x2*)&out[2 * i] = p;
}

// ---------------------------------------------------------------------------
// Flash-decode attention. KVBLK=64, grid (B, NSPLIT=8), block 512 (8 waves).
// Raw no-drain barriers; K/V reg prefetch 1 tile ahead (counted vmcnt).
// kv-reduce fused (16 partials); slot row patched post-staging.
// Swapped QK^T: mfma(K, Q); Q is pre-scaled bf16.
// ---------------------------------------------------------------------------
#define NSPLIT 8
#define CHUNK_T 8
#define KVSPLIT 16

__global__ __launch_bounds__(512, 4)
void attn_fwd(const float* __restrict__ kc, const float* __restrict__ vc,
              const unsigned short* __restrict__ qb, const float* __restrict__ kvp,
              const int* __restrict__ seq_lens, const int* __restrict__ slot_map,
              float* __restrict__ Opart, float* __restrict__ m_ws, float* __restrict__ l_ws)
{
    __shared__ __align__(16) unsigned short Ks [64 * 136];   // [s][d], 68-dword stride
    __shared__ __align__(16) unsigned short Vts[128 * 72];   // [d][s-pair], 36-dword stride
    __shared__ __align__(16) unsigned short Ps [128 * 72];   // [h][s-pair], 36-dword stride
    __shared__ float knew_s[128];
    __shared__ float vnew_s[128];

    const int b = blockIdx.x, split = blockIdx.y;
    const int seq = seq_lens[b], slot = slot_map[b];
    const int nt = (seq + 63) >> 6;
    const int t0 = split * CHUNK_T;
    const int t1 = min(t0 + CHUNK_T, nt);
    const int slotTile = slot >> 6;

    const int tid = threadIdx.x, w = tid >> 6, l = tid & 63, lg = l >> 4, l15 = l & 15;
    const int h = 16 * w + l15;

    float m_run = -__builtin_inff(), l_run = 0.0f;

    if (t0 < t1) {
        // ---- fused kv reduction (only needed if slot row in range)
        if (slotTile >= t0 && slotTile < t1 && tid < 256) {
            float s = 0.f;
#pragma unroll
            for (int j = 0; j < KVSPLIT; j++) s += kvp[j * 32768 + b * 256 + tid];
            if (tid < 128) knew_s[tid] = s;
            else           vnew_s[tid - 128] = s;
        }

        // ---- Q fragments (pre-scaled bf16)
        bf16x8 qf[4];
        {
            const unsigned short* qrow = qb + (size_t)b * 16384 + (size_t)h * 128;
#pragma unroll
            for (int ks = 0; ks < 4; ks++)
                qf[ks] = *(const bf16x8*)(qrow + 32 * ks + 8 * lg);
        }

        // ---- staging registers
        f32x4 kReg[4];
        f32x4 vReg[2][2];
        const int kr  = tid >> 3;           // 0..63 s-row
        const int kcb = (tid & 7) * 16;     // 16 floats
        const int vsp = tid & 31;           // s-pair 0..31
        const int vdq = tid >> 5;           // d-quad 0..15

        auto loadKV = [&](int t) {
            const int s0 = t << 6;
            const float* ksrc = kc + ((size_t)b * 4096 + s0 + kr) * 128 + kcb;
#pragma unroll
            for (int c = 0; c < 4; c++) kReg[c] = *(const f32x4*)(ksrc + 4 * c);
#pragma unroll
            for (int i = 0; i < 2; i++) {
                const int d4 = 4 * vdq + 64 * i;
                const float* r1 = vc + ((size_t)b * 4096 + s0 + 2 * vsp) * 128 + d4;
                vReg[i][0] = *(const f32x4*)r1;
                vReg[i][1] = *(const f32x4*)(r1 + 128);
            }
        };
        auto storeKV = [&]() {
            u32x4 w0 = { pack2(kReg[0][0], kReg[0][1]), pack2(kReg[0][2], kReg[0][3]),
                         pack2(kReg[1][0], kReg[1][1]), pack2(kReg[1][2], kReg[1][3]) };
            u32x4 w1 = { pack2(kReg[2][0], kReg[2][1]), pack2(kReg[2][2], kReg[2][3]),
                         pack2(kReg[3][0], kReg[3][1]), pack2(kReg[3][2], kReg[3][3]) };
            *(u32x4*)&Ks[kr * 136 + kcb] = w0;
            *(u32x4*)&Ks[kr * 136 + kcb + 8] = w1;
            unsigned* vt = (unsigned*)Vts;
#pragma unroll
            for (int i = 0; i < 2; i++)
#pragma unroll
                for (int j = 0; j < 4; j++)
                    vt[(4 * vdq + 64 * i + j) * 36 + vsp] = pack2(vReg[i][0][j], vReg[i][1][j]);
        };

        f32x4 accO[8];
        const f32x4 fzero = {0.f, 0.f, 0.f, 0.f};
#pragma unroll
        for (int i = 0; i < 8; i++) accO[i] = fzero;

        loadKV(t0);
        for (int t = t0; t < t1; ++t) {
            const int s0 = t << 6;
            storeKV();
            bar_nodrain();
            if (t == slotTile) {              // block-uniform
                if (tid < 128) {
                    const int sloc = slot & 63;
                    Ks [sloc * 136 + tid] = f2bf(knew_s[tid]);
                    Vts[tid * 72 + sloc]  = f2bf(vnew_s[tid]);
                }
                bar_nodrain();
            }
            if (t + 1 < t1) loadKV(t + 1);
            __builtin_amdgcn_sched_barrier(0);

            // ---- scores^T = K * Q^T
            f32x4 accS[4];
#pragma unroll
            for (int sf = 0; sf < 4; sf++) accS[sf] = fzero;
#pragma unroll
            for (int ks = 0; ks < 4; ks++) {
#pragma unroll
                for (int sf = 0; sf < 4; sf++) {
                    bf16x8 kf = *(const bf16x8*)&Ks[(16 * sf + l15) * 136 + 32 * ks + 8 * lg];
                    accS[sf] = __builtin_amdgcn_mfma_f32_16x16x32_bf16(kf, qf[ks], accS[sf], 0, 0, 0);
                }
            }
            // ---- mask + online softmax (lane's s = s0 + 16*sf + 4*lg + r)
            float tmax = -__builtin_inff();
#pragma unroll
            for (int sf = 0; sf < 4; sf++) {
#pragma unroll
                for (int r = 0; r < 4; r++) {
                    const int s = s0 + 16 * sf + 4 * lg + r;
                    float sc = (s < seq) ? accS[sf][r] : -__builtin_inff();
                    accS[sf][r] = sc;
                    tmax = fmaxf(tmax, sc);
                }
            }
            tmax = fmaxf(tmax, __shfl_xor(tmax, 16));
            tmax = fmaxf(tmax, __shfl_xor(tmax, 32));
            const float mnew = fmaxf(m_run, tmax);
            const float so = __expf(m_run - mnew);
            float lsum = 0.f;
#pragma unroll
            for (int sf = 0; sf < 4; sf++) {
#pragma unroll
                for (int r = 0; r < 4; r++) {
                    const float p = __expf(accS[sf][r] - mnew);
                    accS[sf][r] = p;
                    lsum += p;
                }
            }
            lsum += __shfl_xor(lsum, 16);
            lsum += __shfl_xor(lsum, 32);
            l_run = l_run * so + lsum;
            m_run = mnew;
#pragma unroll
            for (int i = 0; i < 8; i++) accO[i] *= so;

            // ---- P -> LDS (wave-private rows)
            {
                unsigned* pd = (unsigned*)Ps;
#pragma unroll
                for (int sf = 0; sf < 4; sf++) {
                    pd[h * 36 + 8 * sf + 2 * lg + 0] = pack2(accS[sf][0], accS[sf][1]);
                    pd[h * 36 + 8 * sf + 2 * lg + 1] = pack2(accS[sf][2], accS[sf][3]);
                }
            }
            // ---- O^T += V^T * P^T
            bf16x8 pf[2];
#pragma unroll
            for (int ks = 0; ks < 2; ks++)
                pf[ks] = *(const bf16x8*)&Ps[h * 72 + 32 * ks + 8 * lg];
#pragma unroll
            for (int df = 0; df < 8; df++) {
#pragma unroll
                for (int ks = 0; ks < 2; ks++) {
                    bf16x8 vf = *(const bf16x8*)&Vts[(16 * df + l15) * 72 + 32 * ks + 8 * lg];
                    accO[df] = __builtin_amdgcn_mfma_f32_16x16x32_bf16(vf, pf[ks], accO[df], 0, 0, 0);
                }
            }
            bar_nodrain();
        }
        const size_t base = ((size_t)(b * NSPLIT + split)) * 16384 + (size_t)h * 128;
#pragma unroll
        for (int df = 0; df < 8; df++)
            *(f32x4*)&Opart[base + 16 * df + 4 * lg] = accO[df];
    }
    if (lg == 0) {
        m_ws[(b * NSPLIT + split) * 128 + h] = m_run;
        l_ws[(b * NSPLIT + split) * 128 + h] = l_run;
    }
}

// ---------------------------------------------------------------------------
// Combine the 8 S-split partials -> bf16 attn (row-major [128][16384]).
// ---------------------------------------------------------------------------
__global__ __launch_bounds__(256)
void combine8(const float* __restrict__ Opart, const float* __restrict__ m_ws,
              const float* __restrict__ l_ws, unsigned* __restrict__ attn_bf)
{
    const int idx = blockIdx.x * 256 + threadIdx.x;  // 0..524287
    const int d4 = (idx & 31) * 4;
    const int hh = (idx >> 5) & 127;
    const int b = idx >> 12;

    float m = -__builtin_inff();
    float mv[NSPLIT], lv[NSPLIT];
#pragma unroll
    for (int j = 0; j < NSPLIT; j++) {
        mv[j] = m_ws[(b * NSPLIT + j) * 128 + hh];
        lv[j] = l_ws[(b * NSPLIT + j) * 128 + hh];
        m = fmaxf(m, mv[j]);
    }
    f32x4 o = {0.f, 0.f, 0.f, 0.f};
    float lsum = 0.f;
#pragma unroll
    for (int j = 0; j < NSPLIT; j++) {
        const float a = (lv[j] > 0.f) ? __expf(mv[j] - m) : 0.f;
        lsum += a * lv[j];
        if (a > 0.f) {
            f32x4 oj = *(const f32x4*)&Opart[((size_t)(b * NSPLIT + j)) * 16384 + (size_t)hh * 128 + d4];
            o += oj * a;
        }
    }
    o *= (1.0f / lsum);
    u32x2 p = { pack2(o[0], o[1]), pack2(o[2], o[3]) };
    *(u32x2*)&attn_bf[(size_t)b * 8192 + (size_t)hh * 64 + (d4 >> 1)] = p;
}

// ---------------------------------------------------------------------------
extern "C" void kernel_launch(void* const* d_in, const int* in_sizes, int n_in,
                              void* d_out, int out_size, void* d_ws, size_t ws_size,
                              hipStream_t stream)
{
    const float* hidden  = (const float*)d_in[0];
    const float* k_cache = (const float*)d_in[1];
    const float* v_cache = (const float*)d_in[2];
    const float* Wq      = (const float*)d_in[3];
    const float* Wkv     = (const float*)d_in[4];
    const float* Wo      = (const float*)d_in[5];
    const int* slot_map  = (const int*)d_in[7];
    const int* seq_lens  = (const int*)d_in[8];
    float* out = (float*)d_out;

    float* ws      = (float*)d_ws;
    float* hb      = ws;                   //    327,680 f (bf16 128x5120)
    float* qp      = ws + 327680;          //  8,388,608 f (4 splits)
    float* qb      = ws + 8716288;         //  1,048,576 f (bf16 2M)
    float* kvp     = ws + 9764864;         //    524,288 f (16 splits)
    float* attn_bf = ws + 10289152;        //  1,048,576 f (bf16 2M)
    float* Opart   = ws + 11337728;        // 16,777,216 f
    float* m_ws    = ws + 28114944;        //    131,072 f
    float* l_ws    = ws + 28246016;        //    131,072 f
    float* outp    = ws + 28377088;        // 10,485,760 f (16 splits)

    // hidden -> bf16
    cvt_bf16<<<dim3(320), 256, 0, stream>>>(hidden, (unsigned*)hb, 81920);
    // kv partials = hidden_bf @ Wkv[:, :256]   (K-split 16)
    gemm128<0><<<dim3(4 * 16), 256, 0, stream>>>((const unsigned short*)hb, 5120, Wkv, 576, kvp, 256, 320, 16);
    // q partials = hidden_bf @ Wq (nope cols; K-split 4)
    gemm128<1><<<dim3(256 * 4), 256, 0, stream>>>((const unsigned short*)hb, 5120, Wq, 24576, qp, 16384, 1280, 4);
    // q reduce -> scaled bf16
    reduce_q_bf16<<<dim3(2048), 256, 0, stream>>>(qp, (unsigned*)qb);
    // attention (8 chunked S-splits per batch; kv-reduce fused)
    attn_fwd<<<dim3(128, NSPLIT), 512, 0, stream>>>(k_cache, v_cache, (const unsigned short*)qb,
                                                    kvp, seq_lens, slot_map, Opart, m_ws, l_ws);
    combine8<<<dim3(2048), 256, 0, stream>>>(Opart, m_ws, l_ws, (unsigned*)attn_bf);
    // out partials = attn(bf16) @ Wo   (K-split 16)
    gemm128<0><<<dim3(80 * 16), 256, 0, stream>>>((const unsigned short*)attn_bf, 16384, Wo, 5120, outp, 5120, 1024, 16);
    reduce_f32<<<dim3(640), 256, 0, stream>>>(outp, out, 163840, 16);
}